// Round 6
// baseline (118324.084 us; speedup 1.0000x reference)
//
#include <hip/hip_runtime.h>

#define NB 64
#define NT 256
#define NF 512
#define NU 1024
#define NWG 256
#define NTHR 256

__device__ __forceinline__ float sigm(float x) { return 1.f / (1.f + __expf(-x)); }

struct KParams {
  const float *x, *g1, *b1, *g2, *b2;
  const float *Wx, *Wh, *Wf, *Wi, *Wq, *Wk, *Wv, *Wo;
  float *out;
  float *h, *xx, *sp, *lt, *c, *qb, *kb, *vb, *attb, *stats;
  int *bar;
};

// ------- grid barrier: system scope (validated rounds 2-5: completes, no deadlock) -------
__device__ __forceinline__ void grid_barrier(int* cnt, int target, int tid) {
  __syncthreads();
  if (tid == 0) {
    __threadfence_system();
    __hip_atomic_fetch_add(cnt, 1, __ATOMIC_ACQ_REL, __HIP_MEMORY_SCOPE_SYSTEM);
    while (__hip_atomic_load(cnt, __ATOMIC_ACQUIRE, __HIP_MEMORY_SCOPE_SYSTEM) < target)
      __builtin_amdgcn_s_sleep(2);
    __threadfence_system();
  }
  __syncthreads();
}

// All-fp32 persistent kernel. 256 WGs x 256 thr, 1 block/CU, all co-resident.
// Per WG in GEMM phases: 64-col n-tile (lane = col -> coalesced W rows),
// A rows staged in LDS (32 KB) and reused across output rows.
__global__ __launch_bounds__(NTHR, 1) void vecaw_main(KParams p) {
  const int wg = blockIdx.x;
  const int tid = threadIdx.x;
  const int nl = tid & 63;     // column lane within n-tile
  const int wv = tid >> 6;     // wave id 0..3 -> output-row group

  __shared__ __align__(16) float As[8192];          // 32 KB A-stage
  __shared__ float sm_mean[64], sm_rstd[64], att_s[64];

  int bt = 0;

  for (int t = 0; t < NT; ++t) {
    // ================= P1: xx = [x_t | h] @ [Wx; Wh]  (256 WGs: 16 bg x 16 nt, 4b x 64n each) =================
    {
      const int b0 = (wg >> 4) * 4, n0 = (wg & 15) * 64;
      // stage A: 4 rows x 1536 cols (x_t | h), 6144 floats
#pragma unroll
      for (int it = 0; it < 6; ++it) {
        int e = (tid + it * 256) * 4;
        int row = e / 1536, k = e - row * 1536;
        float4 v;
        if (k < 512) v = *(const float4*)(p.x + ((size_t)(b0 + row) * NT + t) * NF + k);
        else         v = *(const float4*)(p.h + (size_t)(b0 + row) * NU + (k - 512));
        *(float4*)(&As[row * 1536 + k]) = v;
      }
      __syncthreads();
      float acc = 0.f;
      const float* Wxp = p.Wx + n0 + nl;
      const float* Whp = p.Wh + n0 + nl;
      const float* Ar = &As[wv * 1536];
#pragma unroll 8
      for (int k = 0; k < 512; ++k) acc = fmaf(Ar[k], Wxp[(size_t)k * NU], acc);
#pragma unroll 8
      for (int k = 0; k < 1024; ++k) acc = fmaf(Ar[512 + k], Whp[(size_t)k * NU], acc);
      p.xx[(size_t)(b0 + wv) * NU + n0 + nl] = acc;
      if (wg == 0) p.stats[tid] = 0.f;   // zero LN accumulators for this step
    }
    grid_barrier(p.bar, bt += NWG, tid);

    // ================= P2: f,i GEMMs + elementwise + LN stat sums (256 WGs, 4b x 64n) =================
    {
      const int b0 = (wg >> 4) * 4, n0 = (wg & 15) * 64;
#pragma unroll
      for (int it = 0; it < 4; ++it) {
        int e = (tid + it * 256) * 4, row = e >> 10, k = e & 1023;
        *(float4*)(&As[row * 1024 + k]) = *(const float4*)(p.xx + (size_t)(b0 + row) * NU + k);
      }
      __syncthreads();
      float aF = 0.f, aI = 0.f;
      const float* Wfp = p.Wf + n0 + nl;
      const float* Wip = p.Wi + n0 + nl;
      const float* Ar = &As[wv * 1024];
#pragma unroll 4
      for (int k = 0; k < 1024; ++k) {
        float a = Ar[k];
        aF = fmaf(a, Wfp[(size_t)k * NU], aF);
        aI = fmaf(a, Wip[(size_t)k * NU], aI);
      }
      const int b = b0 + wv, u = n0 + nl;
      const size_t off = (size_t)b * NU + u;
      float xxv = Ar[u];
      float f = sigm(aF), i = sigm(aI), cand = tanhf(xxv);
      float lt = f * p.c[off] + i * cand;
      float sw = xxv * sigm(xxv);
      float spin = lt + sw;
      float sp = spin * sigm(spin);
      p.lt[off] = lt;
      p.sp[off] = sp;
      // full-wave reduction over the 64 cols (all lanes of wave wv share row b)
      float ss = sp, sq = sp * sp, ls = lt, lq = lt * lt;
#pragma unroll
      for (int m = 1; m < 64; m <<= 1) {
        ss += __shfl_xor(ss, m, 64);
        sq += __shfl_xor(sq, m, 64);
        ls += __shfl_xor(ls, m, 64);
        lq += __shfl_xor(lq, m, 64);
      }
      if (nl == 0) {
        atomicAdd(&p.stats[b], ss);
        atomicAdd(&p.stats[64 + b], sq);
        atomicAdd(&p.stats[128 + b], ls);
        atomicAdd(&p.stats[192 + b], lq);
      }
    }
    grid_barrier(p.bar, bt += NWG, tid);

    // ================= P4: q,k,v = LN1(sp) @ W{q,k,v} (192 WGs, 16b x 64n) + c = LN2(lt) (64 WGs) ====
    {
      if (wg < 192) {
        const int mat = wg >> 6, sub = wg & 63;
        const int b0 = (sub >> 4) * 16, n0 = (sub & 15) * 64;
        if (tid < 64) {
          float m = p.stats[tid] * (1.f / 1024.f);
          float var = p.stats[64 + tid] * (1.f / 1024.f) - m * m;
          sm_mean[tid] = m;
          sm_rstd[tid] = rsqrtf(var + 1e-3f);
        }
        float acc0 = 0.f, acc1 = 0.f, acc2 = 0.f, acc3 = 0.f;
        const float* W = ((mat == 0) ? p.Wq : (mat == 1) ? p.Wk : p.Wv) + n0 + nl;
        for (int kc = 0; kc < 1024; kc += 512) {
          __syncthreads();   // also orders sm_* writes before staging reads (kc=0)
#pragma unroll
          for (int it = 0; it < 8; ++it) {
            int e = (tid + it * 256) * 4, row = e >> 9, k = e & 511;
            int b = b0 + row;
            float m = sm_mean[b], r = sm_rstd[b];
            float4 s = *(const float4*)(p.sp + (size_t)b * NU + kc + k);
            float4 g = *(const float4*)(p.g1 + kc + k);
            float4 be = *(const float4*)(p.b1 + kc + k);
            float4 o;
            o.x = (s.x - m) * r * g.x + be.x;
            o.y = (s.y - m) * r * g.y + be.y;
            o.z = (s.z - m) * r * g.z + be.z;
            o.w = (s.w - m) * r * g.w + be.w;
            *(float4*)(&As[row * 512 + k]) = o;
          }
          __syncthreads();
          const float* Wk2 = W + (size_t)kc * NU;
#pragma unroll 4
          for (int k = 0; k < 512; ++k) {
            float w = Wk2[(size_t)k * NU];
            acc0 = fmaf(As[(wv) * 512 + k], w, acc0);
            acc1 = fmaf(As[(wv + 4) * 512 + k], w, acc1);
            acc2 = fmaf(As[(wv + 8) * 512 + k], w, acc2);
            acc3 = fmaf(As[(wv + 12) * 512 + k], w, acc3);
          }
        }
        float* dst = (mat == 0) ? p.qb : (mat == 1) ? p.kb : p.vb;
        dst[(size_t)(b0 + wv) * NU + n0 + nl] = acc0;
        dst[(size_t)(b0 + wv + 4) * NU + n0 + nl] = acc1;
        dst[(size_t)(b0 + wv + 8) * NU + n0 + nl] = acc2;
        dst[(size_t)(b0 + wv + 12) * NU + n0 + nl] = acc3;
      } else {
        const int tile = wg - 192;
        if (tid < 64) {
          float m = p.stats[128 + tid] * (1.f / 1024.f);
          float var = p.stats[192 + tid] * (1.f / 1024.f) - m * m;
          sm_mean[tid] = m;
          sm_rstd[tid] = rsqrtf(var + 1e-3f);
        }
        __syncthreads();
        for (int e = tid; e < 1024; e += 256) {
          int b = e >> 4, u = tile * 16 + (e & 15);
          size_t off = (size_t)b * NU + u;
          p.c[off] = (p.lt[off] - sm_mean[b]) * sm_rstd[b] * p.g2[u] + p.b2[u];
        }
      }
    }
    grid_barrier(p.bar, bt += NWG, tid);

    // ================= P5a: per-batch 8x8 attention (64 WGs) =================
    if (wg < 64) {
#pragma unroll
      for (int it = 0; it < 3; ++it) {
        int e = (tid + it * 256) * 4, which = e >> 10, d = e & 1023;
        const float* src = (which == 0) ? p.qb : (which == 1) ? p.kb : p.vb;
        *(float4*)(&As[e]) = *(const float4*)(src + (size_t)wg * NU + d);
      }
      __syncthreads();
      if (tid < 64) {
        int h = tid >> 3, g = tid & 7;
        float s = 0.f;
#pragma unroll 8
        for (int d = 0; d < 128; ++d) s = fmaf(As[h * 128 + d], As[1024 + g * 128 + d], s);
        att_s[tid] = s * 0.08838834764831845f;   // 1/sqrt(128)
      }
      __syncthreads();
      if (tid < 8) {
        float mx = -1e30f;
#pragma unroll
        for (int g = 0; g < 8; ++g) mx = fmaxf(mx, att_s[tid * 8 + g]);
        float e8[8], sum = 0.f;
#pragma unroll
        for (int g = 0; g < 8; ++g) { e8[g] = __expf(att_s[tid * 8 + g] - mx); sum += e8[g]; }
        float inv = 1.f / sum;
#pragma unroll
        for (int g = 0; g < 8; ++g) att_s[tid * 8 + g] = e8[g] * inv;
      }
      __syncthreads();
      for (int idx = tid; idx < 1024; idx += 256) {
        int h = idx >> 7, d = idx & 127;
        float a = 0.f;
#pragma unroll
        for (int g = 0; g < 8; ++g) a = fmaf(att_s[h * 8 + g], As[2048 + g * 128 + d], a);
        p.attb[(size_t)wg * NU + idx] = a;
      }
    }
    grid_barrier(p.bar, bt += NWG, tid);

    // ================= P5b: out = LN1(sp) + att @ Wo; h <- out (256 WGs, 4b x 64n) =================
    {
      const int b0 = (wg >> 4) * 4, n0 = (wg & 15) * 64;
      if (tid < 64) {
        float m = p.stats[tid] * (1.f / 1024.f);
        float var = p.stats[64 + tid] * (1.f / 1024.f) - m * m;
        sm_mean[tid] = m;
        sm_rstd[tid] = rsqrtf(var + 1e-3f);
      }
#pragma unroll
      for (int it = 0; it < 4; ++it) {
        int e = (tid + it * 256) * 4, row = e >> 10, k = e & 1023;
        *(float4*)(&As[row * 1024 + k]) = *(const float4*)(p.attb + (size_t)(b0 + row) * NU + k);
      }
      __syncthreads();
      float acc = 0.f;
      const float* Wop = p.Wo + n0 + nl;
      const float* Ar = &As[wv * 1024];
#pragma unroll 8
      for (int k = 0; k < 1024; ++k) acc = fmaf(Ar[k], Wop[(size_t)k * NU], acc);
      const int b = b0 + wv, u = n0 + nl;
      const size_t off = (size_t)b * NU + u;
      float sln = (p.sp[off] - sm_mean[b]) * sm_rstd[b] * p.g1[u] + p.b1[u];
      float o = sln + acc;
      p.out[((size_t)b * NT + t) * NU + u] = o;
      p.h[off] = o;
    }
    grid_barrier(p.bar, bt += NWG, tid);
  }
}

extern "C" void kernel_launch(void* const* d_in, const int* in_sizes, int n_in,
                              void* d_out, int out_size, void* d_ws, size_t ws_size,
                              hipStream_t stream) {
  (void)in_sizes; (void)n_in; (void)out_size; (void)ws_size;
  const float* x  = (const float*)d_in[0];
  const float* Wx = (const float*)d_in[1];
  const float* Wh = (const float*)d_in[2];
  const float* Wq = (const float*)d_in[3];
  const float* Wk = (const float*)d_in[4];
  const float* Wv = (const float*)d_in[5];
  const float* Wo = (const float*)d_in[6];
  const float* Wf = (const float*)d_in[7];
  const float* Wi = (const float*)d_in[8];
  const float* g1 = (const float*)d_in[9];
  const float* b1 = (const float*)d_in[10];
  const float* g2 = (const float*)d_in[11];
  const float* b2 = (const float*)d_in[12];

  // ~2.3 MB fp32 workspace
  char* pp = (char*)d_ws;
  auto take = [&](size_t bytes) { char* r = pp; pp += (bytes + 255) & ~(size_t)255; return r; };
  int*   bar   = (int*)take(256);
  float* stats = (float*)take(256 * 4);
  float* h     = (float*)take(64 * 1024 * 4);
  float* c     = (float*)take(64 * 1024 * 4);
  float* xx    = (float*)take(64 * 1024 * 4);
  float* lt    = (float*)take(64 * 1024 * 4);
  float* sp    = (float*)take(64 * 1024 * 4);
  float* qb    = (float*)take(64 * 1024 * 4);
  float* kb    = (float*)take(64 * 1024 * 4);
  float* vb    = (float*)take(64 * 1024 * 4);
  float* attb  = (float*)take(64 * 1024 * 4);

  // zero barrier + stats + h + c (contiguous prefix)
  hipMemsetAsync(d_ws, 0, 256 + 1024 + 64 * 1024 * 4 + 64 * 1024 * 4, stream);

  KParams kp;
  kp.x = x; kp.g1 = g1; kp.b1 = b1; kp.g2 = g2; kp.b2 = b2;
  kp.Wx = Wx; kp.Wh = Wh; kp.Wf = Wf; kp.Wi = Wi;
  kp.Wq = Wq; kp.Wk = Wk; kp.Wv = Wv; kp.Wo = Wo;
  kp.out = (float*)d_out;
  kp.h = h; kp.xx = xx; kp.sp = sp; kp.lt = lt; kp.c = c;
  kp.qb = qb; kp.kb = kb; kp.vb = vb; kp.attb = attb;
  kp.stats = stats; kp.bar = bar;

  vecaw_main<<<dim3(NWG), dim3(NTHR), 0, stream>>>(kp);
}

// Round 7
// 81966.370 us; speedup vs baseline: 1.4436x; 1.4436x over previous
//
#include <hip/hip_runtime.h>

#define NB 64
#define NT 256
#define NF 512
#define NU 1024
#define NWG 256
#define NTHR 256

__device__ __forceinline__ float sigm(float x) { return 1.f / (1.f + __expf(-x)); }

struct KParams {
  const float *x, *g1, *b1, *g2, *b2;
  const float *Wx, *Wh, *Wf, *Wi, *Wq, *Wk, *Wv, *Wo;
  float *out;
  float *xx_acc, *fi_acc, *qkv_acc, *wo_acc;  // fp32 atomic accumulation targets
  float *h, *c, *lt, *sp, *attb, *stats, *zr; // zr = contiguous (xx|fi|qkv) region
  int *bar;
};

// ---- grid barrier: agent scope (device) — proven protocol from round 6, cheaper scope ----
__device__ __forceinline__ void grid_barrier(int* cnt, int target, int tid) {
  __syncthreads();
  if (tid == 0) {
    __threadfence();
    __hip_atomic_fetch_add(cnt, 1, __ATOMIC_ACQ_REL, __HIP_MEMORY_SCOPE_AGENT);
    while (__hip_atomic_load(cnt, __ATOMIC_ACQUIRE, __HIP_MEMORY_SCOPE_AGENT) < target)
      __builtin_amdgcn_s_sleep(2);
    __threadfence();
  }
  __syncthreads();
}

// ---- one 64x64 output tile, K-span = nchunks*64, LDS-staged A and W, atomic accumulate ----
// A: row-major [64 x K] with row stride a_ld (optionally LayerNorm'd during staging).
// W: row-major [K x NU]; tile transposed+swizzled into LDS as Wl[col][k].
__device__ __forceinline__ void gemm_tile(
    float* As, float* Wl,
    const float* __restrict__ Abase, int a_ld,
    const float* __restrict__ W, int n0, int k0, int nchunks,
    float* __restrict__ dst,
    int ln_mode, const float* __restrict__ g1, const float* __restrict__ b1,
    const float* smm, const float* smr, int tid)
{
  const int cg = tid & 15, rg = tid >> 4;
  const int c0 = cg * 4, r0 = rg * 4;
  float4 acc0 = {0,0,0,0}, acc1 = {0,0,0,0}, acc2 = {0,0,0,0}, acc3 = {0,0,0,0};

  for (int cc = 0; cc < nchunks; ++cc) {
    const int kc = k0 + cc * 64;
    __syncthreads();
    // stage A 64x64 (coalesced 256B per 16 lanes)
#pragma unroll
    for (int it = 0; it < 4; ++it) {
      int idx = tid + it * 256;
      int r = idx >> 4, k4 = (idx & 15) << 2;
      float4 v = *(const float4*)(Abase + (size_t)r * a_ld + kc + k4);
      if (ln_mode) {
        float m = smm[r], rs = smr[r];
        float4 g = *(const float4*)(g1 + kc + k4);
        float4 be = *(const float4*)(b1 + kc + k4);
        v.x = (v.x - m) * rs * g.x + be.x;
        v.y = (v.y - m) * rs * g.y + be.y;
        v.z = (v.z - m) * rs * g.z + be.z;
        v.w = (v.w - m) * rs * g.w + be.w;
      }
      *(float4*)(&As[r * 68 + k4]) = v;
    }
    // stage W 64x64: transpose to Wl[col][k], XOR-swizzle k-blocks by col-group
#pragma unroll
    for (int it = 0; it < 4; ++it) {
      int idx = tid + it * 256;
      int kk = idx >> 4, cgs = idx & 15;
      float4 v = *(const float4*)(W + (size_t)(kc + kk) * NU + n0 + cgs * 4);
      int sw = (((kk >> 2) ^ cgs) & 15) << 2;
      int base = (cgs * 4) * 68 + sw + (kk & 3);
      Wl[base] = v.x; Wl[base + 68] = v.y; Wl[base + 136] = v.z; Wl[base + 204] = v.w;
    }
    __syncthreads();
    // 4x4 register-tile accumulate over the 64-k chunk
#pragma unroll
    for (int kk = 0; kk < 64; kk += 4) {
      int sw = ((((kk >> 2) ^ cg) & 15) << 2);
      const float4 w0 = *(const float4*)(&Wl[(c0 + 0) * 68 + sw]);
      const float4 w1 = *(const float4*)(&Wl[(c0 + 1) * 68 + sw]);
      const float4 w2 = *(const float4*)(&Wl[(c0 + 2) * 68 + sw]);
      const float4 w3 = *(const float4*)(&Wl[(c0 + 3) * 68 + sw]);
      const float4 a0 = *(const float4*)(&As[(r0 + 0) * 68 + kk]);
      const float4 a1 = *(const float4*)(&As[(r0 + 1) * 68 + kk]);
      const float4 a2 = *(const float4*)(&As[(r0 + 2) * 68 + kk]);
      const float4 a3 = *(const float4*)(&As[(r0 + 3) * 68 + kk]);
#define DOT4(ac, av) \
      ac.x = fmaf(av.x, w0.x, fmaf(av.y, w0.y, fmaf(av.z, w0.z, fmaf(av.w, w0.w, ac.x)))); \
      ac.y = fmaf(av.x, w1.x, fmaf(av.y, w1.y, fmaf(av.z, w1.z, fmaf(av.w, w1.w, ac.y)))); \
      ac.z = fmaf(av.x, w2.x, fmaf(av.y, w2.y, fmaf(av.z, w2.z, fmaf(av.w, w2.w, ac.z)))); \
      ac.w = fmaf(av.x, w3.x, fmaf(av.y, w3.y, fmaf(av.z, w3.z, fmaf(av.w, w3.w, ac.w))));
      DOT4(acc0, a0) DOT4(acc1, a1) DOT4(acc2, a2) DOT4(acc3, a3)
#undef DOT4
    }
  }
  // accumulate partials (16 per thread)
  float* d0 = dst + (size_t)(r0 + 0) * NU + n0 + c0;
  float* d1 = dst + (size_t)(r0 + 1) * NU + n0 + c0;
  float* d2 = dst + (size_t)(r0 + 2) * NU + n0 + c0;
  float* d3 = dst + (size_t)(r0 + 3) * NU + n0 + c0;
  atomicAdd(d0+0, acc0.x); atomicAdd(d0+1, acc0.y); atomicAdd(d0+2, acc0.z); atomicAdd(d0+3, acc0.w);
  atomicAdd(d1+0, acc1.x); atomicAdd(d1+1, acc1.y); atomicAdd(d1+2, acc1.z); atomicAdd(d1+3, acc1.w);
  atomicAdd(d2+0, acc2.x); atomicAdd(d2+1, acc2.y); atomicAdd(d2+2, acc2.z); atomicAdd(d2+3, acc2.w);
  atomicAdd(d3+0, acc3.x); atomicAdd(d3+1, acc3.y); atomicAdd(d3+2, acc3.z); atomicAdd(d3+3, acc3.w);
}

__global__ __launch_bounds__(NTHR, 1) void vecaw_main(KParams p) {
  const int wg = blockIdx.x;
  const int tid = threadIdx.x;

  __shared__ __align__(16) float As[64 * 68];
  __shared__ __align__(16) float Wl[64 * 68];
  __shared__ float smm[64], smr[64], red[16], att_s[64];

  int bt = 0;

  for (int t = 0; t < NT; ++t) {
    // ===== P1: xx += h@Wh (256 tasks) + x_t@Wx (128 tasks; WGs<128 do both) =====
    {
      const int nt = wg & 15;
      gemm_tile(As, Wl, p.h, NU, p.Wh, nt * 64, (wg >> 4) * 64, 1,
                p.xx_acc, 0, nullptr, nullptr, nullptr, nullptr, tid);
      if (wg < 128) {
        gemm_tile(As, Wl, p.x + (size_t)t * NF, NT * NF, p.Wx, nt * 64, (wg >> 4) * 64, 1,
                  p.xx_acc, 0, nullptr, nullptr, nullptr, nullptr, tid);
      }
      if (wg == 255) p.stats[tid] = 0.f;   // stats(t-1) consumed in P6(t-1)
    }
    grid_barrier(p.bar, bt += NWG, tid);

    // ===== P2: f,i partial GEMMs (2 mats x 16 nt x 8 ks = 256 WGs) =====
    {
      const int mat = wg >> 7, sub = wg & 127;
      gemm_tile(As, Wl, p.xx_acc, NU, mat ? p.Wi : p.Wf, (sub & 15) * 64, (sub >> 4) * 128, 2,
                p.fi_acc + (size_t)mat * 65536, 0, nullptr, nullptr, nullptr, nullptr, tid);
    }
    grid_barrier(p.bar, bt += NWG, tid);

    // ===== P3: elementwise + LN stats + zero wo_acc =====
    {
      const int b = wg >> 2;
      const int u = ((wg & 3) << 8) + tid;
      const size_t off = (size_t)b * NU + u;
      float xxv = p.xx_acc[off];
      float f = sigm(p.fi_acc[off]);
      float i = sigm(p.fi_acc[65536 + off]);
      float lt = f * p.c[off] + i * tanhf(xxv);
      float sw = xxv * sigm(xxv);
      float spin = lt + sw;
      float sp = spin * sigm(spin);
      p.lt[off] = lt;
      p.sp[off] = sp;
      float s0 = sp, s1 = sp * sp, s2 = lt, s3 = lt * lt;
#pragma unroll
      for (int m = 1; m < 64; m <<= 1) {
        s0 += __shfl_xor(s0, m, 64); s1 += __shfl_xor(s1, m, 64);
        s2 += __shfl_xor(s2, m, 64); s3 += __shfl_xor(s3, m, 64);
      }
      if ((tid & 63) == 0) {
        int wv = tid >> 6;
        red[wv * 4 + 0] = s0; red[wv * 4 + 1] = s1;
        red[wv * 4 + 2] = s2; red[wv * 4 + 3] = s3;
      }
      __syncthreads();
      if (tid == 0) {
        atomicAdd(&p.stats[b],       red[0] + red[4] + red[8]  + red[12]);
        atomicAdd(&p.stats[64 + b],  red[1] + red[5] + red[9]  + red[13]);
        atomicAdd(&p.stats[128 + b], red[2] + red[6] + red[10] + red[14]);
        atomicAdd(&p.stats[192 + b], red[3] + red[7] + red[11] + red[15]);
      }
      p.wo_acc[((size_t)wg << 8) + tid] = 0.f;   // consumed P6(t-1); written P5b(t)
    }
    grid_barrier(p.bar, bt += NWG, tid);

    // ===== P4: q,k,v partial GEMMs w/ LN1-on-stage (192 WGs) + c=LN2(lt) (64 WGs) =====
    if (wg < 192) {
      if (tid < 64) {
        float m = p.stats[tid] * (1.f / 1024.f);
        float var = p.stats[64 + tid] * (1.f / 1024.f) - m * m;
        smm[tid] = m;
        smr[tid] = rsqrtf(var + 1e-3f);
      }
      const int mat = wg >> 6, sub = wg & 63;
      const float* W = (mat == 0) ? p.Wq : (mat == 1) ? p.Wk : p.Wv;
      gemm_tile(As, Wl, p.sp, NU, W, (sub & 15) * 64, (sub >> 4) * 256, 4,
                p.qkv_acc + (size_t)mat * 65536, 1, p.g1, p.b1, smm, smr, tid);
    } else {
      const int b = wg - 192;
      float m = p.stats[128 + b] * (1.f / 1024.f);
      float var = p.stats[192 + b] * (1.f / 1024.f) - m * m;
      float rs = rsqrtf(var + 1e-3f);
      for (int u = tid; u < 1024; u += 256) {
        size_t off = (size_t)b * NU + u;
        p.c[off] = (p.lt[off] - m) * rs * p.g2[u] + p.b2[u];
      }
    }
    grid_barrier(p.bar, bt += NWG, tid);

    // ===== P5a: per-batch 8x8 attention (64 WGs) =====
    if (wg < 64) {
      const int b = wg;
      for (int e = tid; e < 3072; e += 256) {
        int m = e >> 10, d = e & 1023;
        As[e] = p.qkv_acc[(size_t)m * 65536 + (size_t)b * NU + d];
      }
      __syncthreads();
      if (tid < 64) {
        int h = tid >> 3, g = tid & 7;
        float s = 0.f;
#pragma unroll 8
        for (int d = 0; d < 128; ++d) s = fmaf(As[h * 128 + d], As[1024 + g * 128 + d], s);
        att_s[tid] = s * 0.08838834764831845f;  // 1/sqrt(128)
      }
      __syncthreads();
      if (tid < 8) {
        float mx = -1e30f;
#pragma unroll
        for (int g = 0; g < 8; ++g) mx = fmaxf(mx, att_s[tid * 8 + g]);
        float e8[8], sum = 0.f;
#pragma unroll
        for (int g = 0; g < 8; ++g) { e8[g] = __expf(att_s[tid * 8 + g] - mx); sum += e8[g]; }
        float inv = 1.f / sum;
#pragma unroll
        for (int g = 0; g < 8; ++g) att_s[tid * 8 + g] = e8[g] * inv;
      }
      __syncthreads();
      for (int idx = tid; idx < 1024; idx += 256) {
        int h = idx >> 7, d = idx & 127;
        float a = 0.f;
#pragma unroll
        for (int g = 0; g < 8; ++g) a = fmaf(att_s[h * 8 + g], As[2048 + g * 128 + d], a);
        p.attb[(size_t)b * NU + idx] = a;
      }
    }
    grid_barrier(p.bar, bt += NWG, tid);

    // ===== P5b: wo_acc += att@Wo (128 WGs) + zero xx/fi/qkv accum (128 WGs) =====
    if (wg < 128) {
      gemm_tile(As, Wl, p.attb, NU, p.Wo, (wg & 15) * 64, (wg >> 4) * 128, 2,
                p.wo_acc, 0, nullptr, nullptr, nullptr, nullptr, tid);
    } else {
      const int z = wg - 128;            // zero 384K floats (xx|fi|qkv) for next step
      float4* zr = (float4*)p.zr;
#pragma unroll
      for (int it = 0; it < 3; ++it) {
        float4 zero = {0.f, 0.f, 0.f, 0.f};
        zr[(size_t)z * 768 + tid + it * 256] = zero;
      }
    }
    grid_barrier(p.bar, bt += NWG, tid);

    // ===== P6: out = LN1(sp) + wo_acc; h <- out =====
    {
      const int b = wg >> 2;
      const int u = ((wg & 3) << 8) + tid;
      const size_t off = (size_t)b * NU + u;
      float m = p.stats[b] * (1.f / 1024.f);
      float var = p.stats[64 + b] * (1.f / 1024.f) - m * m;
      float rs = rsqrtf(var + 1e-3f);
      float sln = (p.sp[off] - m) * rs * p.g1[u] + p.b1[u];
      float o = sln + p.wo_acc[off];
      p.out[((size_t)b * NT + t) * NU + u] = o;
      p.h[off] = o;
    }
    grid_barrier(p.bar, bt += NWG, tid);
  }
}

extern "C" void kernel_launch(void* const* d_in, const int* in_sizes, int n_in,
                              void* d_out, int out_size, void* d_ws, size_t ws_size,
                              hipStream_t stream) {
  (void)in_sizes; (void)n_in; (void)out_size; (void)ws_size;
  const float* x  = (const float*)d_in[0];
  const float* Wx = (const float*)d_in[1];
  const float* Wh = (const float*)d_in[2];
  const float* Wq = (const float*)d_in[3];
  const float* Wk = (const float*)d_in[4];
  const float* Wv = (const float*)d_in[5];
  const float* Wo = (const float*)d_in[6];
  const float* Wf = (const float*)d_in[7];
  const float* Wi = (const float*)d_in[8];
  const float* g1 = (const float*)d_in[9];
  const float* b1 = (const float*)d_in[10];
  const float* g2 = (const float*)d_in[11];
  const float* b2 = (const float*)d_in[12];

  // ~3.4 MB fp32 workspace
  char* pp = (char*)d_ws;
  auto take = [&](size_t bytes) { char* r = pp; pp += (bytes + 255) & ~(size_t)255; return r; };
  int*   bar     = (int*)take(256);
  float* stats   = (float*)take(256 * 4);
  float* zr      = (float*)take((size_t)(65536 + 131072 + 196608) * 4); // xx|fi|qkv contiguous
  float* xx_acc  = zr;
  float* fi_acc  = zr + 65536;
  float* qkv_acc = zr + 65536 + 131072;
  float* wo_acc  = (float*)take(65536 * 4);
  float* h       = (float*)take(65536 * 4);
  float* c       = (float*)take(65536 * 4);
  float* lt      = (float*)take(65536 * 4);
  float* sp      = (float*)take(65536 * 4);
  float* attb    = (float*)take(65536 * 4);

  // zero everything (barrier, stats, all accum buffers, h, c at t=0)
  hipMemsetAsync(d_ws, 0, (size_t)(pp - (char*)d_ws), stream);

  KParams kp;
  kp.x = x; kp.g1 = g1; kp.b1 = b1; kp.g2 = g2; kp.b2 = b2;
  kp.Wx = Wx; kp.Wh = Wh; kp.Wf = Wf; kp.Wi = Wi;
  kp.Wq = Wq; kp.Wk = Wk; kp.Wv = Wv; kp.Wo = Wo;
  kp.out = (float*)d_out;
  kp.xx_acc = xx_acc; kp.fi_acc = fi_acc; kp.qkv_acc = qkv_acc; kp.wo_acc = wo_acc;
  kp.h = h; kp.c = c; kp.lt = lt; kp.sp = sp; kp.attb = attb;
  kp.stats = stats; kp.zr = zr; kp.bar = bar;

  // 256 blocks x 256 thr, ~36 KB LDS -> 1 block/CU on 256 CUs, all co-resident
  vecaw_main<<<dim3(NWG), dim3(NTHR), 0, stream>>>(kp);
}

// Round 8
// 41728.439 us; speedup vs baseline: 2.8356x; 1.9643x over previous
//
#include <hip/hip_runtime.h>

#define NB 64
#define NT 256
#define NF 512
#define NU 1024
#define NWG 256
#define NTHR 256
#define SLICE 65536   // 64*1024 floats per partial K-slice

__device__ __forceinline__ float sigm(float x) { return 1.f / (1.f + __expf(-x)); }

struct KParams {
  const float *x, *g1, *b1, *g2, *b2;
  const float *Wx, *Wh, *Wf, *Wi, *Wq, *Wk, *Wv, *Wo;
  float *out;
  float *xxp, *fip, *qkvp, *wop;          // K-split partial slices (plain stores)
  float *xxm, *lt, *sp, *c, *attb, *stats; // stats double-buffered [2][256]
  int *flags, *rel;
};

// ---- distributed-flag grid barrier: per-WG arrival lines + WG0 gather + broadcast release ----
// (r7 evidence: single-counter barrier = 256 contended RMWs on one line ~= 40us/barrier)
__device__ __forceinline__ void grid_barrier(int* flags, int* rel, int epoch, int wg, int tid) {
  __syncthreads();
  if (wg == 0) {
    if (tid > 0) {   // thread i polls WG i's private flag line
      while (__hip_atomic_load(&flags[tid * 16], __ATOMIC_RELAXED, __HIP_MEMORY_SCOPE_AGENT) < epoch)
        __builtin_amdgcn_s_sleep(1);
    }
    __syncthreads();
    if (tid == 0) {
      __threadfence();                     // wb+inv: flush WG0's writes, invalidate stale lines
      __hip_atomic_store(rel, epoch, __ATOMIC_RELAXED, __HIP_MEMORY_SCOPE_AGENT);
    }
    __syncthreads();
  } else {
    if (tid == 0) {
      __threadfence();                     // release: write back this XCD's dirty lines
      __hip_atomic_store(&flags[wg * 16], epoch, __ATOMIC_RELAXED, __HIP_MEMORY_SCOPE_AGENT);
      while (__hip_atomic_load(rel, __ATOMIC_RELAXED, __HIP_MEMORY_SCOPE_AGENT) < epoch)
        __builtin_amdgcn_s_sleep(1);
      __threadfence();                     // acquire: invalidate so new reads are fresh
    }
    __syncthreads();
  }
}

// ---- one 64x64 output tile over K = nchunks*64, LDS-staged A and W, PLAIN-STORE epilogue ----
// A-stage modes: 0 = direct rows  1 = h-on-the-fly (LN1(sp)+sum(wop), optional out write)
//               2 = sum 6 xx partials (optional xxm write)   3 = LN1(sp)
__device__ __forceinline__ void gemm_tile(
    float* As, float* Wl, const float* smm, const float* smr,
    int mode, const float* A0, size_t a_ld,
    const float* g1, const float* b1, const float* wop,
    float* outw, size_t out_ld,
    const float* __restrict__ W, int n0, int k0, int nchunks,
    float* __restrict__ dst, int tid)
{
  const int cg = tid & 15, rg = tid >> 4;
  const int c0 = cg * 4, r0 = rg * 4;
  float4 acc0 = {0,0,0,0}, acc1 = {0,0,0,0}, acc2 = {0,0,0,0}, acc3 = {0,0,0,0};

  for (int cc = 0; cc < nchunks; ++cc) {
    const int kc = k0 + cc * 64;
    __syncthreads();
    // stage A 64x64
#pragma unroll
    for (int it = 0; it < 4; ++it) {
      int idx = tid + it * 256;
      int r = idx >> 4, k4 = (idx & 15) << 2;
      int col = kc + k4;
      float4 v;
      if (mode == 0) {
        v = *(const float4*)(A0 + (size_t)r * a_ld + col);
      } else if (mode == 1) {
        if (A0) {
          float m = smm[r], rs = smr[r];
          float4 s  = *(const float4*)(A0 + (size_t)r * NU + col);
          float4 g  = *(const float4*)(g1 + col);
          float4 be = *(const float4*)(b1 + col);
          float4 w0 = *(const float4*)(wop + 0 * SLICE + (size_t)r * NU + col);
          float4 w1 = *(const float4*)(wop + 1 * SLICE + (size_t)r * NU + col);
          float4 w2 = *(const float4*)(wop + 2 * SLICE + (size_t)r * NU + col);
          float4 w3 = *(const float4*)(wop + 3 * SLICE + (size_t)r * NU + col);
          v.x = (s.x - m) * rs * g.x + be.x + w0.x + w1.x + w2.x + w3.x;
          v.y = (s.y - m) * rs * g.y + be.y + w0.y + w1.y + w2.y + w3.y;
          v.z = (s.z - m) * rs * g.z + be.z + w0.z + w1.z + w2.z + w3.z;
          v.w = (s.w - m) * rs * g.w + be.w + w0.w + w1.w + w2.w + w3.w;
        } else { v.x = v.y = v.z = v.w = 0.f; }
        if (outw) *(float4*)(outw + (size_t)r * out_ld + col) = v;
      } else if (mode == 2) {
        v.x = v.y = v.z = v.w = 0.f;
#pragma unroll
        for (int s = 0; s < 6; ++s) {
          float4 q = *(const float4*)(A0 + (size_t)s * SLICE + (size_t)r * NU + col);
          v.x += q.x; v.y += q.y; v.z += q.z; v.w += q.w;
        }
        if (outw) *(float4*)(outw + (size_t)r * out_ld + col) = v;
      } else {  // mode 3: LN1(sp)
        float m = smm[r], rs = smr[r];
        float4 s  = *(const float4*)(A0 + (size_t)r * NU + col);
        float4 g  = *(const float4*)(g1 + col);
        float4 be = *(const float4*)(b1 + col);
        v.x = (s.x - m) * rs * g.x + be.x;
        v.y = (s.y - m) * rs * g.y + be.y;
        v.z = (s.z - m) * rs * g.z + be.z;
        v.w = (s.w - m) * rs * g.w + be.w;
      }
      *(float4*)(&As[r * 68 + k4]) = v;
    }
    // stage W 64x64: transpose to Wl[col][k], XOR-swizzled (validated r7)
#pragma unroll
    for (int it = 0; it < 4; ++it) {
      int idx = tid + it * 256;
      int kk = idx >> 4, cgs = idx & 15;
      float4 v = *(const float4*)(W + (size_t)(kc + kk) * NU + n0 + cgs * 4);
      int sw = (((kk >> 2) ^ cgs) & 15) << 2;
      int base = (cgs * 4) * 68 + sw + (kk & 3);
      Wl[base] = v.x; Wl[base + 68] = v.y; Wl[base + 136] = v.z; Wl[base + 204] = v.w;
    }
    __syncthreads();
    // 4x4 register-tile accumulate (validated r7)
#pragma unroll
    for (int kk = 0; kk < 64; kk += 4) {
      int sw = ((((kk >> 2) ^ cg) & 15) << 2);
      const float4 w0 = *(const float4*)(&Wl[(c0 + 0) * 68 + sw]);
      const float4 w1 = *(const float4*)(&Wl[(c0 + 1) * 68 + sw]);
      const float4 w2 = *(const float4*)(&Wl[(c0 + 2) * 68 + sw]);
      const float4 w3 = *(const float4*)(&Wl[(c0 + 3) * 68 + sw]);
      const float4 a0 = *(const float4*)(&As[(r0 + 0) * 68 + kk]);
      const float4 a1 = *(const float4*)(&As[(r0 + 1) * 68 + kk]);
      const float4 a2 = *(const float4*)(&As[(r0 + 2) * 68 + kk]);
      const float4 a3 = *(const float4*)(&As[(r0 + 3) * 68 + kk]);
#define DOT4(ac, av) \
      ac.x = fmaf(av.x, w0.x, fmaf(av.y, w0.y, fmaf(av.z, w0.z, fmaf(av.w, w0.w, ac.x)))); \
      ac.y = fmaf(av.x, w1.x, fmaf(av.y, w1.y, fmaf(av.z, w1.z, fmaf(av.w, w1.w, ac.y)))); \
      ac.z = fmaf(av.x, w2.x, fmaf(av.y, w2.y, fmaf(av.z, w2.z, fmaf(av.w, w2.w, ac.z)))); \
      ac.w = fmaf(av.x, w3.x, fmaf(av.y, w3.y, fmaf(av.z, w3.z, fmaf(av.w, w3.w, ac.w))));
      DOT4(acc0, a0) DOT4(acc1, a1) DOT4(acc2, a2) DOT4(acc3, a3)
#undef DOT4
    }
  }
  // plain coalesced float4 stores — each (slice, nt, row) owned by exactly one WG
  *(float4*)(dst + (size_t)(r0 + 0) * NU + n0 + c0) = acc0;
  *(float4*)(dst + (size_t)(r0 + 1) * NU + n0 + c0) = acc1;
  *(float4*)(dst + (size_t)(r0 + 2) * NU + n0 + c0) = acc2;
  *(float4*)(dst + (size_t)(r0 + 3) * NU + n0 + c0) = acc3;
}

__global__ __launch_bounds__(NTHR, 1) void vecaw_main(KParams p) {
  const int wg = blockIdx.x;
  const int tid = threadIdx.x;

  __shared__ __align__(16) float As[64 * 68];
  __shared__ __align__(16) float Wl[64 * 68];
  __shared__ float smm[64], smr[64], red[16], att_s[64];

  int epoch = 0;

  for (int t = 0; t < NT; ++t) {
    const int par = t & 1, prevpar = par ^ 1;

    // ===== P1: xx partials (Wh 64 WGs K=256 + Wx 32 WGs K=256); h on-the-fly; out(t-1) =====
    if (wg < 64) {
      const int nt = wg & 15, ks = wg >> 4;
      if (tid < 64 && t > 0) {
        float m = p.stats[prevpar * 256 + tid] * (1.f / 1024.f);
        float var = p.stats[prevpar * 256 + 64 + tid] * (1.f / 1024.f) - m * m;
        smm[tid] = m;
        smr[tid] = rsqrtf(var + 1e-3f);
      }
      float* outw = (nt == 0 && t > 0) ? (p.out + (size_t)(t - 1) * NU) : nullptr;
      gemm_tile(As, Wl, smm, smr, 1, (t > 0) ? p.sp : nullptr, NU,
                p.g1, p.b1, p.wop, outw, (size_t)NT * NU,
                p.Wh, nt * 64, ks * 256, 4, p.xxp + (size_t)ks * SLICE, tid);
    } else if (wg < 96) {
      const int idx = wg - 64, nt = idx & 15, ks = idx >> 4;
      gemm_tile(As, Wl, nullptr, nullptr, 0, p.x + (size_t)t * NF, (size_t)NT * NF,
                nullptr, nullptr, nullptr, nullptr, 0,
                p.Wx, nt * 64, ks * 256, 4, p.xxp + (size_t)(4 + ks) * SLICE, tid);
    }
    grid_barrier(p.flags, p.rel, ++epoch, wg, tid);

    // ===== P2: f,i partials (128 WGs, K=256); materialize xx =====
    if (wg < 128) {
      const int mat = wg >> 6, idx = wg & 63, nt = idx & 15, ks = idx >> 4;
      float* outw = (mat == 0 && nt == 0) ? p.xxm : nullptr;
      gemm_tile(As, Wl, nullptr, nullptr, 2, p.xxp, NU,
                nullptr, nullptr, nullptr, outw, NU,
                mat ? p.Wi : p.Wf, nt * 64, ks * 256, 4,
                p.fip + (size_t)(mat * 4 + ks) * SLICE, tid);
    }
    grid_barrier(p.flags, p.rel, ++epoch, wg, tid);

    // ===== P3: elementwise + LN stats (all 256 WGs; 1 elem/thread) =====
    {
      const int b = wg >> 2;
      const int u = ((wg & 3) << 8) + tid;
      const size_t off = (size_t)b * NU + u;
      float xxv = p.xxm[off];
      float fs = p.fip[off] + p.fip[SLICE + off] + p.fip[2 * SLICE + off] + p.fip[3 * SLICE + off];
      float is = p.fip[4 * SLICE + off] + p.fip[5 * SLICE + off] + p.fip[6 * SLICE + off] + p.fip[7 * SLICE + off];
      float f = sigm(fs), i = sigm(is);
      float ltv = f * p.c[off] + i * tanhf(xxv);
      float sw = xxv * sigm(xxv);
      float spin = ltv + sw;
      float spv = spin * sigm(spin);
      p.lt[off] = ltv;
      p.sp[off] = spv;
      float s0 = spv, s1 = spv * spv, s2 = ltv, s3 = ltv * ltv;
#pragma unroll
      for (int m = 1; m < 64; m <<= 1) {
        s0 += __shfl_xor(s0, m, 64); s1 += __shfl_xor(s1, m, 64);
        s2 += __shfl_xor(s2, m, 64); s3 += __shfl_xor(s3, m, 64);
      }
      if ((tid & 63) == 0) {
        int wv = tid >> 6;
        red[wv * 4 + 0] = s0; red[wv * 4 + 1] = s1;
        red[wv * 4 + 2] = s2; red[wv * 4 + 3] = s3;
      }
      __syncthreads();
      if (tid == 0) {
        atomicAdd(&p.stats[par * 256 + b],       red[0] + red[4] + red[8]  + red[12]);
        atomicAdd(&p.stats[par * 256 + 64 + b],  red[1] + red[5] + red[9]  + red[13]);
        atomicAdd(&p.stats[par * 256 + 128 + b], red[2] + red[6] + red[10] + red[14]);
        atomicAdd(&p.stats[par * 256 + 192 + b], red[3] + red[7] + red[11] + red[15]);
      }
      if (wg == 255) p.stats[prevpar * 256 + tid] = 0.f;  // prev parity consumed in P1 this step
    }
    grid_barrier(p.flags, p.rel, ++epoch, wg, tid);

    // ===== P4: q,k,v partials with LN1-on-stage (192 WGs, K=256) + c = LN2(lt) (64 WGs) =====
    if (wg < 192) {
      if (tid < 64) {
        float m = p.stats[par * 256 + tid] * (1.f / 1024.f);
        float var = p.stats[par * 256 + 64 + tid] * (1.f / 1024.f) - m * m;
        smm[tid] = m;
        smr[tid] = rsqrtf(var + 1e-3f);
      }
      const int mat = wg >> 6, idx = wg & 63, nt = idx & 15, ks = idx >> 4;
      const float* W = (mat == 0) ? p.Wq : (mat == 1) ? p.Wk : p.Wv;
      gemm_tile(As, Wl, smm, smr, 3, p.sp, NU,
                p.g1, p.b1, nullptr, nullptr, 0,
                W, nt * 64, ks * 256, 4, p.qkvp + (size_t)(mat * 4 + ks) * SLICE, tid);
    } else {
      const int b = wg - 192;
      float m = p.stats[par * 256 + 128 + b] * (1.f / 1024.f);
      float var = p.stats[par * 256 + 192 + b] * (1.f / 1024.f) - m * m;
      float rs = rsqrtf(var + 1e-3f);
      for (int u = tid; u < 1024; u += 256) {
        size_t off = (size_t)b * NU + u;
        p.c[off] = (p.lt[off] - m) * rs * p.g2[u] + p.b2[u];
      }
    }
    grid_barrier(p.flags, p.rel, ++epoch, wg, tid);

    // ===== P5a: per-batch 8x8 attention (64 WGs); q,k,v summed from partials =====
    if (wg < 64) {
      const int b = wg;
      for (int e = tid; e < 3072; e += 256) {
        const int m = e >> 10, d = e & 1023;
        const float* base = p.qkvp + (size_t)(m * 4) * SLICE + (size_t)b * NU + d;
        As[e] = base[0] + base[SLICE] + base[2 * SLICE] + base[3 * SLICE];
      }
      __syncthreads();
      if (tid < 64) {
        int h = tid >> 3, g = tid & 7;
        float s = 0.f;
#pragma unroll 8
        for (int d = 0; d < 128; ++d) s = fmaf(As[h * 128 + d], As[1024 + g * 128 + d], s);
        att_s[tid] = s * 0.08838834764831845f;   // 1/sqrt(128)
      }
      __syncthreads();
      if (tid < 8) {
        float mx = -1e30f;
#pragma unroll
        for (int g = 0; g < 8; ++g) mx = fmaxf(mx, att_s[tid * 8 + g]);
        float e8[8], sum = 0.f;
#pragma unroll
        for (int g = 0; g < 8; ++g) { e8[g] = __expf(att_s[tid * 8 + g] - mx); sum += e8[g]; }
        float inv = 1.f / sum;
#pragma unroll
        for (int g = 0; g < 8; ++g) att_s[tid * 8 + g] = e8[g] * inv;
      }
      __syncthreads();
      for (int idx = tid; idx < 1024; idx += 256) {
        int h = idx >> 7, d = idx & 127;
        float a = 0.f;
#pragma unroll
        for (int g = 0; g < 8; ++g) a = fmaf(att_s[h * 8 + g], As[2048 + g * 128 + d], a);
        p.attb[(size_t)b * NU + idx] = a;
      }
    }
    grid_barrier(p.flags, p.rel, ++epoch, wg, tid);

    // ===== P5b: wo partials (64 WGs, K=256) =====
    if (wg < 64) {
      const int nt = wg & 15, ks = wg >> 4;
      gemm_tile(As, Wl, nullptr, nullptr, 0, p.attb, NU,
                nullptr, nullptr, nullptr, nullptr, 0,
                p.Wo, nt * 64, ks * 256, 4, p.wop + (size_t)ks * SLICE, tid);
    }
    grid_barrier(p.flags, p.rel, ++epoch, wg, tid);
  }

  // ===== final epilogue: out(255) = LN1(sp) + sum(wop) =====
  {
    const int b = wg >> 2;
    const int u = ((wg & 3) << 8) + tid;
    const size_t off = (size_t)b * NU + u;
    float m = p.stats[256 + b] * (1.f / 1024.f);            // par(255) = 1
    float var = p.stats[256 + 64 + b] * (1.f / 1024.f) - m * m;
    float rs = rsqrtf(var + 1e-3f);
    float wo = p.wop[off] + p.wop[SLICE + off] + p.wop[2 * SLICE + off] + p.wop[3 * SLICE + off];
    p.out[((size_t)b * NT + 255) * NU + u] = (p.sp[off] - m) * rs * p.g1[u] + p.b1[u] + wo;
  }
}

extern "C" void kernel_launch(void* const* d_in, const int* in_sizes, int n_in,
                              void* d_out, int out_size, void* d_ws, size_t ws_size,
                              hipStream_t stream) {
  (void)in_sizes; (void)n_in; (void)out_size; (void)ws_size;
  const float* x  = (const float*)d_in[0];
  const float* Wx = (const float*)d_in[1];
  const float* Wh = (const float*)d_in[2];
  const float* Wq = (const float*)d_in[3];
  const float* Wk = (const float*)d_in[4];
  const float* Wv = (const float*)d_in[5];
  const float* Wo = (const float*)d_in[6];
  const float* Wf = (const float*)d_in[7];
  const float* Wi = (const float*)d_in[8];
  const float* g1 = (const float*)d_in[9];
  const float* b1 = (const float*)d_in[10];
  const float* g2 = (const float*)d_in[11];
  const float* b2 = (const float*)d_in[12];

  char* pp = (char*)d_ws;
  auto take = [&](size_t bytes) { char* r = pp; pp += (bytes + 255) & ~(size_t)255; return r; };
  // --- memset region: flags | rel | stats | c ---
  int*   flags = (int*)take(256 * 16 * 4);     // one 64B line per WG
  int*   rel   = (int*)take(256);
  float* stats = (float*)take(2 * 256 * 4);    // double-buffered
  float* c     = (float*)take((size_t)SLICE * 4);
  size_t zbytes = (size_t)(pp - (char*)d_ws);
  // --- rest (fully overwritten each step before read) ---
  float* xxp   = (float*)take((size_t)6 * SLICE * 4);
  float* fip   = (float*)take((size_t)8 * SLICE * 4);
  float* qkvp  = (float*)take((size_t)12 * SLICE * 4);
  float* wop   = (float*)take((size_t)4 * SLICE * 4);
  float* xxm   = (float*)take((size_t)SLICE * 4);
  float* lt    = (float*)take((size_t)SLICE * 4);
  float* sp    = (float*)take((size_t)SLICE * 4);
  float* attb  = (float*)take((size_t)SLICE * 4);

  hipMemsetAsync(d_ws, 0, zbytes, stream);

  KParams kp;
  kp.x = x; kp.g1 = g1; kp.b1 = b1; kp.g2 = g2; kp.b2 = b2;
  kp.Wx = Wx; kp.Wh = Wh; kp.Wf = Wf; kp.Wi = Wi;
  kp.Wq = Wq; kp.Wk = Wk; kp.Wv = Wv; kp.Wo = Wo;
  kp.out = (float*)d_out;
  kp.xxp = xxp; kp.fip = fip; kp.qkvp = qkvp; kp.wop = wop;
  kp.xxm = xxm; kp.lt = lt; kp.sp = sp; kp.c = c; kp.attb = attb;
  kp.stats = stats; kp.flags = flags; kp.rel = rel;

  // 256 blocks x 256 thr, ~36 KB LDS -> 1 block/CU on 256 CUs, all co-resident
  vecaw_main<<<dim3(NWG), dim3(NTHR), 0, stream>>>(kp);
}

// Round 9
// 41606.464 us; speedup vs baseline: 2.8439x; 1.0029x over previous
//
#include <hip/hip_runtime.h>

#define NB 64
#define NT 256
#define NF 512
#define NU 1024
#define NWG 256
#define NTHR 256
#define SLICE 65536   // 64*1024 floats per partial K-slice

__device__ __forceinline__ float sigm(float x) { return 1.f / (1.f + __expf(-x)); }

struct KParams {
  const float *x, *g1, *b1, *g2, *b2;
  const float *Wx, *Wh, *Wf, *Wi, *Wq, *Wk, *Wv, *Wo;
  float *out;
  float *xxp, *fip, *qkvp, *wop;          // K-split partial slices (plain stores)
  float *xxm, *lt, *sp, *c, *attb, *stats; // stats double-buffered [2][256]
  int *flags, *grel;
};

// ---- distributed-flag grid barrier w/ HIERARCHICAL release ----
// r8 evidence: parallel arrival is fine, but 255 WGs polling ONE release line
// serialize at the coherence point (~80ns ea ~= 20us). Fan out release over 16
// group lines (<=15 pollers each, parallel across L3 slices).
__device__ __forceinline__ void grid_barrier(int* flags, int* grel, int epoch, int wg, int tid) {
  __syncthreads();
  if (wg == 0) {
    if (tid > 0) {   // thread i polls WG i's private arrival line (255 distinct lines)
      while (__hip_atomic_load(&flags[tid * 16], __ATOMIC_RELAXED, __HIP_MEMORY_SCOPE_AGENT) < epoch)
        __builtin_amdgcn_s_sleep(1);
    }
    __syncthreads();
    if (tid == 0) __threadfence();       // wb+inv: WG0's (and its XCD's) writes to L3
    __syncthreads();                     // fence complete before any release store
    if (tid < 16)                        // release: 16 group lines, one writer each
      __hip_atomic_store(&grel[tid * 16], epoch, __ATOMIC_RELAXED, __HIP_MEMORY_SCOPE_AGENT);
    __syncthreads();
  } else {
    if (tid == 0) {
      __threadfence();                   // release: write back this XCD's dirty lines
      __hip_atomic_store(&flags[wg * 16], epoch, __ATOMIC_RELAXED, __HIP_MEMORY_SCOPE_AGENT);
      const int g = wg >> 4;             // poll own group's release line (<=15 pollers)
      while (__hip_atomic_load(&grel[g * 16], __ATOMIC_RELAXED, __HIP_MEMORY_SCOPE_AGENT) < epoch)
        __builtin_amdgcn_s_sleep(1);
      __threadfence();                   // acquire: invalidate so new reads are fresh
    }
    __syncthreads();
  }
}

// ---- one 64x64 output tile over K = nchunks*64, LDS-staged A and W, PLAIN-STORE epilogue ----
// A-stage modes: 0 = direct rows  1 = h-on-the-fly (LN1(sp)+sum(wop), optional out write)
//               2 = sum 6 xx partials (optional xxm write)   3 = LN1(sp)
__device__ __forceinline__ void gemm_tile(
    float* As, float* Wl, const float* smm, const float* smr,
    int mode, const float* A0, size_t a_ld,
    const float* g1, const float* b1, const float* wop,
    float* outw, size_t out_ld,
    const float* __restrict__ W, int n0, int k0, int nchunks,
    float* __restrict__ dst, int tid)
{
  const int cg = tid & 15, rg = tid >> 4;
  const int c0 = cg * 4, r0 = rg * 4;
  float4 acc0 = {0,0,0,0}, acc1 = {0,0,0,0}, acc2 = {0,0,0,0}, acc3 = {0,0,0,0};

  for (int cc = 0; cc < nchunks; ++cc) {
    const int kc = k0 + cc * 64;
    __syncthreads();
    // stage A 64x64
#pragma unroll
    for (int it = 0; it < 4; ++it) {
      int idx = tid + it * 256;
      int r = idx >> 4, k4 = (idx & 15) << 2;
      int col = kc + k4;
      float4 v;
      if (mode == 0) {
        v = *(const float4*)(A0 + (size_t)r * a_ld + col);
      } else if (mode == 1) {
        if (A0) {
          float m = smm[r], rs = smr[r];
          float4 s  = *(const float4*)(A0 + (size_t)r * NU + col);
          float4 g  = *(const float4*)(g1 + col);
          float4 be = *(const float4*)(b1 + col);
          float4 w0 = *(const float4*)(wop + 0 * SLICE + (size_t)r * NU + col);
          float4 w1 = *(const float4*)(wop + 1 * SLICE + (size_t)r * NU + col);
          float4 w2 = *(const float4*)(wop + 2 * SLICE + (size_t)r * NU + col);
          float4 w3 = *(const float4*)(wop + 3 * SLICE + (size_t)r * NU + col);
          v.x = (s.x - m) * rs * g.x + be.x + w0.x + w1.x + w2.x + w3.x;
          v.y = (s.y - m) * rs * g.y + be.y + w0.y + w1.y + w2.y + w3.y;
          v.z = (s.z - m) * rs * g.z + be.z + w0.z + w1.z + w2.z + w3.z;
          v.w = (s.w - m) * rs * g.w + be.w + w0.w + w1.w + w2.w + w3.w;
        } else { v.x = v.y = v.z = v.w = 0.f; }
        if (outw) *(float4*)(outw + (size_t)r * out_ld + col) = v;
      } else if (mode == 2) {
        v.x = v.y = v.z = v.w = 0.f;
#pragma unroll
        for (int s = 0; s < 6; ++s) {
          float4 q = *(const float4*)(A0 + (size_t)s * SLICE + (size_t)r * NU + col);
          v.x += q.x; v.y += q.y; v.z += q.z; v.w += q.w;
        }
        if (outw) *(float4*)(outw + (size_t)r * out_ld + col) = v;
      } else {  // mode 3: LN1(sp)
        float m = smm[r], rs = smr[r];
        float4 s  = *(const float4*)(A0 + (size_t)r * NU + col);
        float4 g  = *(const float4*)(g1 + col);
        float4 be = *(const float4*)(b1 + col);
        v.x = (s.x - m) * rs * g.x + be.x;
        v.y = (s.y - m) * rs * g.y + be.y;
        v.z = (s.z - m) * rs * g.z + be.z;
        v.w = (s.w - m) * rs * g.w + be.w;
      }
      *(float4*)(&As[r * 68 + k4]) = v;
    }
    // stage W 64x64: transpose to Wl[col][k], XOR-swizzled (validated r7)
#pragma unroll
    for (int it = 0; it < 4; ++it) {
      int idx = tid + it * 256;
      int kk = idx >> 4, cgs = idx & 15;
      float4 v = *(const float4*)(W + (size_t)(kc + kk) * NU + n0 + cgs * 4);
      int sw = (((kk >> 2) ^ cgs) & 15) << 2;
      int base = (cgs * 4) * 68 + sw + (kk & 3);
      Wl[base] = v.x; Wl[base + 68] = v.y; Wl[base + 136] = v.z; Wl[base + 204] = v.w;
    }
    __syncthreads();
    // 4x4 register-tile accumulate (validated r7)
#pragma unroll
    for (int kk = 0; kk < 64; kk += 4) {
      int sw = ((((kk >> 2) ^ cg) & 15) << 2);
      const float4 w0 = *(const float4*)(&Wl[(c0 + 0) * 68 + sw]);
      const float4 w1 = *(const float4*)(&Wl[(c0 + 1) * 68 + sw]);
      const float4 w2 = *(const float4*)(&Wl[(c0 + 2) * 68 + sw]);
      const float4 w3 = *(const float4*)(&Wl[(c0 + 3) * 68 + sw]);
      const float4 a0 = *(const float4*)(&As[(r0 + 0) * 68 + kk]);
      const float4 a1 = *(const float4*)(&As[(r0 + 1) * 68 + kk]);
      const float4 a2 = *(const float4*)(&As[(r0 + 2) * 68 + kk]);
      const float4 a3 = *(const float4*)(&As[(r0 + 3) * 68 + kk]);
#define DOT4(ac, av) \
      ac.x = fmaf(av.x, w0.x, fmaf(av.y, w0.y, fmaf(av.z, w0.z, fmaf(av.w, w0.w, ac.x)))); \
      ac.y = fmaf(av.x, w1.x, fmaf(av.y, w1.y, fmaf(av.z, w1.z, fmaf(av.w, w1.w, ac.y)))); \
      ac.z = fmaf(av.x, w2.x, fmaf(av.y, w2.y, fmaf(av.z, w2.z, fmaf(av.w, w2.w, ac.z)))); \
      ac.w = fmaf(av.x, w3.x, fmaf(av.y, w3.y, fmaf(av.z, w3.z, fmaf(av.w, w3.w, ac.w))));
      DOT4(acc0, a0) DOT4(acc1, a1) DOT4(acc2, a2) DOT4(acc3, a3)
#undef DOT4
    }
  }
  // plain coalesced float4 stores — each (slice, nt, row) owned by exactly one WG
  *(float4*)(dst + (size_t)(r0 + 0) * NU + n0 + c0) = acc0;
  *(float4*)(dst + (size_t)(r0 + 1) * NU + n0 + c0) = acc1;
  *(float4*)(dst + (size_t)(r0 + 2) * NU + n0 + c0) = acc2;
  *(float4*)(dst + (size_t)(r0 + 3) * NU + n0 + c0) = acc3;
}

__global__ __launch_bounds__(NTHR, 1) void vecaw_main(KParams p) {
  const int wg = blockIdx.x;
  const int tid = threadIdx.x;

  __shared__ __align__(16) float As[64 * 68];
  __shared__ __align__(16) float Wl[64 * 68];
  __shared__ float smm[64], smr[64], red[16], att_s[64];

  int epoch = 0;

  for (int t = 0; t < NT; ++t) {
    const int par = t & 1, prevpar = par ^ 1;

    // ===== P1: xx partials (Wh 64 WGs K=256 + Wx 32 WGs K=256); h on-the-fly; out(t-1) =====
    if (wg < 64) {
      const int nt = wg & 15, ks = wg >> 4;
      if (tid < 64 && t > 0) {
        float m = p.stats[prevpar * 256 + tid] * (1.f / 1024.f);
        float var = p.stats[prevpar * 256 + 64 + tid] * (1.f / 1024.f) - m * m;
        smm[tid] = m;
        smr[tid] = rsqrtf(var + 1e-3f);
      }
      float* outw = (nt == 0 && t > 0) ? (p.out + (size_t)(t - 1) * NU) : nullptr;
      gemm_tile(As, Wl, smm, smr, 1, (t > 0) ? p.sp : nullptr, NU,
                p.g1, p.b1, p.wop, outw, (size_t)NT * NU,
                p.Wh, nt * 64, ks * 256, 4, p.xxp + (size_t)ks * SLICE, tid);
    } else if (wg < 96) {
      const int idx = wg - 64, nt = idx & 15, ks = idx >> 4;
      gemm_tile(As, Wl, nullptr, nullptr, 0, p.x + (size_t)t * NF, (size_t)NT * NF,
                nullptr, nullptr, nullptr, nullptr, 0,
                p.Wx, nt * 64, ks * 256, 4, p.xxp + (size_t)(4 + ks) * SLICE, tid);
    }
    grid_barrier(p.flags, p.grel, ++epoch, wg, tid);

    // ===== P2: f,i partials (128 WGs, K=256); materialize xx =====
    if (wg < 128) {
      const int mat = wg >> 6, idx = wg & 63, nt = idx & 15, ks = idx >> 4;
      float* outw = (mat == 0 && nt == 0) ? p.xxm : nullptr;
      gemm_tile(As, Wl, nullptr, nullptr, 2, p.xxp, NU,
                nullptr, nullptr, nullptr, outw, NU,
                mat ? p.Wi : p.Wf, nt * 64, ks * 256, 4,
                p.fip + (size_t)(mat * 4 + ks) * SLICE, tid);
    }
    grid_barrier(p.flags, p.grel, ++epoch, wg, tid);

    // ===== P3: elementwise + LN stats (all 256 WGs; 1 elem/thread) =====
    {
      const int b = wg >> 2;
      const int u = ((wg & 3) << 8) + tid;
      const size_t off = (size_t)b * NU + u;
      float xxv = p.xxm[off];
      float fs = p.fip[off] + p.fip[SLICE + off] + p.fip[2 * SLICE + off] + p.fip[3 * SLICE + off];
      float is = p.fip[4 * SLICE + off] + p.fip[5 * SLICE + off] + p.fip[6 * SLICE + off] + p.fip[7 * SLICE + off];
      float f = sigm(fs), i = sigm(is);
      float ltv = f * p.c[off] + i * tanhf(xxv);
      float sw = xxv * sigm(xxv);
      float spin = ltv + sw;
      float spv = spin * sigm(spin);
      p.lt[off] = ltv;
      p.sp[off] = spv;
      float s0 = spv, s1 = spv * spv, s2 = ltv, s3 = ltv * ltv;
#pragma unroll
      for (int m = 1; m < 64; m <<= 1) {
        s0 += __shfl_xor(s0, m, 64); s1 += __shfl_xor(s1, m, 64);
        s2 += __shfl_xor(s2, m, 64); s3 += __shfl_xor(s3, m, 64);
      }
      if ((tid & 63) == 0) {
        int wv = tid >> 6;
        red[wv * 4 + 0] = s0; red[wv * 4 + 1] = s1;
        red[wv * 4 + 2] = s2; red[wv * 4 + 3] = s3;
      }
      __syncthreads();
      if (tid == 0) {
        atomicAdd(&p.stats[par * 256 + b],       red[0] + red[4] + red[8]  + red[12]);
        atomicAdd(&p.stats[par * 256 + 64 + b],  red[1] + red[5] + red[9]  + red[13]);
        atomicAdd(&p.stats[par * 256 + 128 + b], red[2] + red[6] + red[10] + red[14]);
        atomicAdd(&p.stats[par * 256 + 192 + b], red[3] + red[7] + red[11] + red[15]);
      }
      if (wg == 255) p.stats[prevpar * 256 + tid] = 0.f;  // prev parity consumed in P1 this step
    }
    grid_barrier(p.flags, p.grel, ++epoch, wg, tid);

    // ===== P4: q,k,v partials with LN1-on-stage (192 WGs, K=256) + c = LN2(lt) (64 WGs) =====
    if (wg < 192) {
      if (tid < 64) {
        float m = p.stats[par * 256 + tid] * (1.f / 1024.f);
        float var = p.stats[par * 256 + 64 + tid] * (1.f / 1024.f) - m * m;
        smm[tid] = m;
        smr[tid] = rsqrtf(var + 1e-3f);
      }
      const int mat = wg >> 6, idx = wg & 63, nt = idx & 15, ks = idx >> 4;
      const float* W = (mat == 0) ? p.Wq : (mat == 1) ? p.Wk : p.Wv;
      gemm_tile(As, Wl, smm, smr, 3, p.sp, NU,
                p.g1, p.b1, nullptr, nullptr, 0,
                W, nt * 64, ks * 256, 4, p.qkvp + (size_t)(mat * 4 + ks) * SLICE, tid);
    } else {
      const int b = wg - 192;
      float m = p.stats[par * 256 + 128 + b] * (1.f / 1024.f);
      float var = p.stats[par * 256 + 192 + b] * (1.f / 1024.f) - m * m;
      float rs = rsqrtf(var + 1e-3f);
      for (int u = tid; u < 1024; u += 256) {
        size_t off = (size_t)b * NU + u;
        p.c[off] = (p.lt[off] - m) * rs * p.g2[u] + p.b2[u];
      }
    }
    grid_barrier(p.flags, p.grel, ++epoch, wg, tid);

    // ===== P5a: per-batch 8x8 attention (64 WGs); q,k,v summed from partials =====
    if (wg < 64) {
      const int b = wg;
      for (int e = tid; e < 3072; e += 256) {
        const int m = e >> 10, d = e & 1023;
        const float* base = p.qkvp + (size_t)(m * 4) * SLICE + (size_t)b * NU + d;
        As[e] = base[0] + base[SLICE] + base[2 * SLICE] + base[3 * SLICE];
      }
      __syncthreads();
      if (tid < 64) {
        int h = tid >> 3, g = tid & 7;
        float s = 0.f;
#pragma unroll 8
        for (int d = 0; d < 128; ++d) s = fmaf(As[h * 128 + d], As[1024 + g * 128 + d], s);
        att_s[tid] = s * 0.08838834764831845f;   // 1/sqrt(128)
      }
      __syncthreads();
      if (tid < 8) {
        float mx = -1e30f;
#pragma unroll
        for (int g = 0; g < 8; ++g) mx = fmaxf(mx, att_s[tid * 8 + g]);
        float e8[8], sum = 0.f;
#pragma unroll
        for (int g = 0; g < 8; ++g) { e8[g] = __expf(att_s[tid * 8 + g] - mx); sum += e8[g]; }
        float inv = 1.f / sum;
#pragma unroll
        for (int g = 0; g < 8; ++g) att_s[tid * 8 + g] = e8[g] * inv;
      }
      __syncthreads();
      for (int idx = tid; idx < 1024; idx += 256) {
        int h = idx >> 7, d = idx & 127;
        float a = 0.f;
#pragma unroll
        for (int g = 0; g < 8; ++g) a = fmaf(att_s[h * 8 + g], As[2048 + g * 128 + d], a);
        p.attb[(size_t)b * NU + idx] = a;
      }
    }
    grid_barrier(p.flags, p.grel, ++epoch, wg, tid);

    // ===== P5b: wo partials (64 WGs, K=256) =====
    if (wg < 64) {
      const int nt = wg & 15, ks = wg >> 4;
      gemm_tile(As, Wl, nullptr, nullptr, 0, p.attb, NU,
                nullptr, nullptr, nullptr, nullptr, 0,
                p.Wo, nt * 64, ks * 256, 4, p.wop + (size_t)ks * SLICE, tid);
    }
    grid_barrier(p.flags, p.grel, ++epoch, wg, tid);
  }

  // ===== final epilogue: out(255) = LN1(sp) + sum(wop) =====
  {
    const int b = wg >> 2;
    const int u = ((wg & 3) << 8) + tid;
    const size_t off = (size_t)b * NU + u;
    float m = p.stats[256 + b] * (1.f / 1024.f);            // par(255) = 1
    float var = p.stats[256 + 64 + b] * (1.f / 1024.f) - m * m;
    float rs = rsqrtf(var + 1e-3f);
    float wo = p.wop[off] + p.wop[SLICE + off] + p.wop[2 * SLICE + off] + p.wop[3 * SLICE + off];
    p.out[((size_t)b * NT + 255) * NU + u] = (p.sp[off] - m) * rs * p.g1[u] + p.b1[u] + wo;
  }
}

extern "C" void kernel_launch(void* const* d_in, const int* in_sizes, int n_in,
                              void* d_out, int out_size, void* d_ws, size_t ws_size,
                              hipStream_t stream) {
  (void)in_sizes; (void)n_in; (void)out_size; (void)ws_size;
  const float* x  = (const float*)d_in[0];
  const float* Wx = (const float*)d_in[1];
  const float* Wh = (const float*)d_in[2];
  const float* Wq = (const float*)d_in[3];
  const float* Wk = (const float*)d_in[4];
  const float* Wv = (const float*)d_in[5];
  const float* Wo = (const float*)d_in[6];
  const float* Wf = (const float*)d_in[7];
  const float* Wi = (const float*)d_in[8];
  const float* g1 = (const float*)d_in[9];
  const float* b1 = (const float*)d_in[10];
  const float* g2 = (const float*)d_in[11];
  const float* b2 = (const float*)d_in[12];

  char* pp = (char*)d_ws;
  auto take = [&](size_t bytes) { char* r = pp; pp += (bytes + 255) & ~(size_t)255; return r; };
  // --- memset region: flags | grel | stats | c ---
  int*   flags = (int*)take(256 * 16 * 4);     // one 64B line per WG
  int*   grel  = (int*)take(16 * 16 * 4);      // one 64B line per 16-WG group
  float* stats = (float*)take(2 * 256 * 4);    // double-buffered
  float* c     = (float*)take((size_t)SLICE * 4);
  size_t zbytes = (size_t)(pp - (char*)d_ws);
  // --- rest (fully overwritten each step before read) ---
  float* xxp   = (float*)take((size_t)6 * SLICE * 4);
  float* fip   = (float*)take((size_t)8 * SLICE * 4);
  float* qkvp  = (float*)take((size_t)12 * SLICE * 4);
  float* wop   = (float*)take((size_t)4 * SLICE * 4);
  float* xxm   = (float*)take((size_t)SLICE * 4);
  float* lt    = (float*)take((size_t)SLICE * 4);
  float* sp    = (float*)take((size_t)SLICE * 4);
  float* attb  = (float*)take((size_t)SLICE * 4);

  hipMemsetAsync(d_ws, 0, zbytes, stream);

  KParams kp;
  kp.x = x; kp.g1 = g1; kp.b1 = b1; kp.g2 = g2; kp.b2 = b2;
  kp.Wx = Wx; kp.Wh = Wh; kp.Wf = Wf; kp.Wi = Wi;
  kp.Wq = Wq; kp.Wk = Wk; kp.Wv = Wv; kp.Wo = Wo;
  kp.out = (float*)d_out;
  kp.xxp = xxp; kp.fip = fip; kp.qkvp = qkvp; kp.wop = wop;
  kp.xxm = xxm; kp.lt = lt; kp.sp = sp; kp.c = c; kp.attb = attb;
  kp.stats = stats; kp.flags = flags; kp.grel = grel;

  // 256 blocks x 256 thr, ~36 KB LDS -> 1 block/CU on 256 CUs, all co-resident
  vecaw_main<<<dim3(NWG), dim3(NTHR), 0, stream>>>(kp);
}